// Round 4
// baseline (482.156 us; speedup 1.0000x reference)
//
#include <hip/hip_runtime.h>
#include <hip/hip_bf16.h>

// RelMultiHeadAttn (Transformer-XL) on MI355X.
// fp32 inputs/outputs; fp16 internal, fp32 accumulate.
// QLEN=1024 MLEN=1024 KLEN=2048 BSZ=2 DMODEL=1024 NH=16 DH=64
// Round 4: materialize E = qr @ rk^T (pre-shift BD) via GEMM; attention
// applies rel_shift as a global gather into E. Attn loop: 3 barriers/tile,
// 37 KB LDS, no windowed-T MFMA.

#define QLENC 1024
#define KLENC 2048
#define BSZC 2
#define DMODELC 1024
#define NHC 16
#define DHC 64

typedef _Float16 half_t;
typedef __attribute__((ext_vector_type(8))) _Float16 f16x8;
typedef __attribute__((ext_vector_type(4))) float f32x4;

// ---------------------------------------------------------------- transpose
// W [K x N] fp32 row-major -> Wt [N x K] fp16 row-major. 64x64 tiles.
__global__ __launch_bounds__(256) void transpose64(const float* __restrict__ W,
                                                   half_t* __restrict__ Wt,
                                                   int K, int N) {
    __shared__ __attribute__((aligned(16))) half_t T[64][72];
    int t = threadIdx.x;
    int n0 = blockIdx.x * 64, k0 = blockIdx.y * 64;
    int r = t >> 2, c = (t & 3) << 4;
    const float4* s = (const float4*)&W[(size_t)(k0 + r) * N + n0 + c];
    float4 f0 = s[0], f1 = s[1], f2 = s[2], f3 = s[3];
    half_t h[16];
    h[0] = (half_t)f0.x; h[1] = (half_t)f0.y; h[2] = (half_t)f0.z; h[3] = (half_t)f0.w;
    h[4] = (half_t)f1.x; h[5] = (half_t)f1.y; h[6] = (half_t)f1.z; h[7] = (half_t)f1.w;
    h[8] = (half_t)f2.x; h[9] = (half_t)f2.y; h[10] = (half_t)f2.z; h[11] = (half_t)f2.w;
    h[12] = (half_t)f3.x; h[13] = (half_t)f3.y; h[14] = (half_t)f3.z; h[15] = (half_t)f3.w;
    *(uint4*)&T[r][c] = *(uint4*)&h[0];
    *(uint4*)&T[r][c + 8] = *(uint4*)&h[8];
    __syncthreads();
    half_t vals[16];
#pragma unroll
    for (int u = 0; u < 16; u++) vals[u] = T[c + u][r];
    *(uint4*)&Wt[(size_t)(n0 + r) * K + k0 + c] = *(uint4*)&vals[0];
    *(uint4*)&Wt[(size_t)(n0 + r) * K + k0 + c + 8] = *(uint4*)&vals[8];
}

// ---------------------------------------------------------------- GEMM
// C = A[M,K] @ Bt[N,K]^T, f16 MFMA 16x16x32, 64x64 tile / 256 threads.
// EPI 0: q projection -> qw (+bias1), qr (+bias2), head-split (fp16)
// EPI 1: kv projection -> kh [b][n][j][d], vt [b][n][d][j] (fp16)
// EPI 2: r projection  -> rk [n][t][d] (fp16)
// EPI 3: plain fp32 [M,ldc] output (A fp16)
// EPI 4: E-gemm, z = b*NH+n: A=qr[z] [1024x64], B=rk[z&15] [2048x64],
//        C fp16 -> E + z*QLEN*KLEN (ldc=2048)
template <int EPI>
__global__ __launch_bounds__(256) void gemm64(
    const void* __restrict__ Ap, const half_t* __restrict__ Bt,
    int K, int lda, int ldb, int ldc,
    void* __restrict__ o1v, void* __restrict__ o2v,
    const float* __restrict__ bias1, const float* __restrict__ bias2) {
    constexpr bool AF32 = (EPI == 0 || EPI == 1 || EPI == 2);
    __shared__ __attribute__((aligned(16))) half_t As[64][72];
    __shared__ __attribute__((aligned(16))) half_t Bs[64][72];

    if (EPI == 4) {
        int bn = blockIdx.z;
        Ap = (const void*)((const half_t*)Ap + (size_t)bn * QLENC * DHC);
        Bt += (size_t)(bn & (NHC - 1)) * KLENC * DHC;
    }

    int t = threadIdx.x;
    int w = t >> 6, ln = t & 63, quad = ln >> 4, l15 = ln & 15;
    int m0 = blockIdx.y * 64, n0 = blockIdx.x * 64;
    int lr = t >> 2, lc = (t & 3) << 4;
    int rbase = 32 * (w >> 1), cbase = 32 * (w & 1);

    f32x4 acc[2][2];
#pragma unroll
    for (int i = 0; i < 2; i++)
#pragma unroll
        for (int j = 0; j < 2; j++) acc[i][j] = (f32x4){0.f, 0.f, 0.f, 0.f};

    for (int k0 = 0; k0 < K; k0 += 64) {
        half_t ah[16];
        if (AF32) {
            const float4* ap = (const float4*)((const float*)Ap + (size_t)(m0 + lr) * lda + k0 + lc);
            float4 a0 = ap[0], a1 = ap[1], a2 = ap[2], a3 = ap[3];
            ah[0] = (half_t)a0.x; ah[1] = (half_t)a0.y; ah[2] = (half_t)a0.z; ah[3] = (half_t)a0.w;
            ah[4] = (half_t)a1.x; ah[5] = (half_t)a1.y; ah[6] = (half_t)a1.z; ah[7] = (half_t)a1.w;
            ah[8] = (half_t)a2.x; ah[9] = (half_t)a2.y; ah[10] = (half_t)a2.z; ah[11] = (half_t)a2.w;
            ah[12] = (half_t)a3.x; ah[13] = (half_t)a3.y; ah[14] = (half_t)a3.z; ah[15] = (half_t)a3.w;
        } else {
            const uint4* ap = (const uint4*)((const half_t*)Ap + (size_t)(m0 + lr) * lda + k0 + lc);
            *(uint4*)&ah[0] = ap[0];
            *(uint4*)&ah[8] = ap[1];
        }
        const uint4* bp = (const uint4*)&Bt[(size_t)(n0 + lr) * ldb + k0 + lc];
        uint4 b0 = bp[0], b1 = bp[1];
        __syncthreads();
        *(uint4*)&As[lr][lc] = *(uint4*)&ah[0];
        *(uint4*)&As[lr][lc + 8] = *(uint4*)&ah[8];
        *(uint4*)&Bs[lr][lc] = b0; *(uint4*)&Bs[lr][lc + 8] = b1;
        __syncthreads();
#pragma unroll
        for (int kk = 0; kk < 2; kk++) {
            f16x8 af[2], bfr[2];
            af[0]  = *(const f16x8*)&As[rbase + l15][kk * 32 + quad * 8];
            af[1]  = *(const f16x8*)&As[rbase + 16 + l15][kk * 32 + quad * 8];
            bfr[0] = *(const f16x8*)&Bs[cbase + l15][kk * 32 + quad * 8];
            bfr[1] = *(const f16x8*)&Bs[cbase + 16 + l15][kk * 32 + quad * 8];
#pragma unroll
            for (int rb = 0; rb < 2; rb++)
#pragma unroll
                for (int cb = 0; cb < 2; cb++)
                    acc[rb][cb] = __builtin_amdgcn_mfma_f32_16x16x32_f16(
                        af[rb], bfr[cb], acc[rb][cb], 0, 0, 0);
        }
    }

    half_t* o1h = (half_t*)o1v;
    half_t* o2h = (half_t*)o2v;
#pragma unroll
    for (int rb = 0; rb < 2; rb++)
#pragma unroll
        for (int cb = 0; cb < 2; cb++)
#pragma unroll
            for (int reg = 0; reg < 4; reg++) {
                int gr = m0 + rbase + 16 * rb + quad * 4 + reg;  // C row
                int gc = n0 + cbase + 16 * cb + l15;             // C col
                float v = acc[rb][cb][reg];
                if (EPI == 0) {
                    int p_ = gr >> 1, b_ = gr & 1, n_ = gc >> 6, d_ = gc & 63;
                    float bb1 = bias1[n_ * 64 + d_];
                    float bb2 = bias2[n_ * 64 + d_];
                    size_t idx = (((size_t)(b_ * NHC + n_)) * QLENC + p_) * DHC + d_;
                    o1h[idx] = (half_t)(v + bb1);
                    o2h[idx] = (half_t)(v + bb2);
                } else if (EPI == 1) {
                    int p_ = gr >> 1, b_ = gr & 1;
                    if (gc < NHC * DHC) {
                        int n_ = gc >> 6, d_ = gc & 63;
                        o1h[(((size_t)(b_ * NHC + n_)) * KLENC + p_) * DHC + d_] = (half_t)v;
                    } else {
                        int c2 = gc - NHC * DHC, n_ = c2 >> 6, d_ = c2 & 63;
                        o2h[(((size_t)(b_ * NHC + n_)) * DHC + d_) * KLENC + p_] = (half_t)v;
                    }
                } else if (EPI == 2) {
                    int n_ = gc >> 6, d_ = gc & 63;
                    o1h[(((size_t)n_) * KLENC + gr) * DHC + d_] = (half_t)v;
                } else if (EPI == 4) {
                    o1h[(size_t)blockIdx.z * QLENC * KLENC + (size_t)gr * ldc + gc] = (half_t)v;
                } else {
                    ((float*)o1v)[(size_t)gr * ldc + gc] = v;
                }
            }
}

// ---------------------------------------------------------------- fused attention
// One block per (head n, 64-row q tile, batch b). 4 waves; wave w owns q rows
// [i0+16w, i0+16w+16). Per 64-col k-tile: stage K/V -> QK^T MFMA with E-band
// global loads in flight -> rel-shift gather -> online softmax -> P via LDS
// -> PV MFMA. E[bn][i][m] = qr_i . rk_m (pre-shift BD):
//   delta = j-i: delta<=1024 -> E[i][1023+delta]
//                delta==1025 -> 0
//                delta>=1026 -> E[i+1][delta-1026]   (i+1<=1022 always)
__global__ __launch_bounds__(256, 2) void attn_fused(
    const half_t* __restrict__ qw, const half_t* __restrict__ kh,
    const half_t* __restrict__ vt, const half_t* __restrict__ E,
    half_t* __restrict__ av) {
    __shared__ __attribute__((aligned(16))) half_t Qs[64][72];
    __shared__ __attribute__((aligned(16))) half_t Ks[64][72];
    __shared__ __attribute__((aligned(16))) half_t Vs[64][72];
    __shared__ __attribute__((aligned(16))) half_t Ps[64][72];

    int n = blockIdx.x, i0 = blockIdx.y * 64, b = blockIdx.z;
    int t = threadIdx.x, w = t >> 6, ln = t & 63, quad = ln >> 4, l15 = ln & 15;
    int lr = t >> 2, lc = (t & 3) << 4;
    int wq = w * 16 + quad * 4;
    size_t bn = (size_t)(b * NHC + n);
    const half_t* En = E + bn * QLENC * KLENC;

    // stage Q tile once (visible after first iteration's s2)
    {
        const uint4* s1 = (const uint4*)&qw[((bn * QLENC) + i0 + lr) * DHC + lc];
        *(uint4*)&Qs[lr][lc] = s1[0];
        *(uint4*)&Qs[lr][lc + 8] = s1[1];
    }

    f32x4 O[4];
#pragma unroll
    for (int i = 0; i < 4; i++) O[i] = (f32x4){0.f, 0.f, 0.f, 0.f};
    float m_old[4] = {-1e30f, -1e30f, -1e30f, -1e30f};
    float lsum[4] = {0.f, 0.f, 0.f, 0.f};
    const float scale = 0.125f;  // 1/sqrt(64)

    for (int jt = 0; jt < KLENC / 64; jt++) {
        int j0 = jt * 64;

        // preload K/V tiles into regs
        const uint4* ks = (const uint4*)&kh[((bn * KLENC) + j0 + lr) * DHC + lc];
        const uint4* vs = (const uint4*)&vt[((bn * DHC) + lr) * KLENC + j0 + lc];
        uint4 k0v = ks[0], k1v = ks[1], v0v = vs[0], v1v = vs[1];

        __syncthreads();  // s1: prior-iter LDS reads (Ks/Vs/Ps/Qs-init) done
        *(uint4*)&Ks[lr][lc] = k0v; *(uint4*)&Ks[lr][lc + 8] = k1v;
        *(uint4*)&Vs[lr][lc] = v0v; *(uint4*)&Vs[lr][lc + 8] = v1v;
        __syncthreads();  // s2

        // E band loads (independent of LDS; in flight during QK MFMA)
        float bdv[4][4];
#pragma unroll
        for (int reg = 0; reg < 4; reg++) {
            int i = i0 + wq + reg;
#pragma unroll
            for (int cb = 0; cb < 4; cb++) {
                int j = j0 + cb * 16 + l15;
                int delta = j - i;
                float v;
                if (delta <= 1024)
                    v = (float)En[(size_t)i * KLENC + 1023 + delta];
                else if (delta == 1025)
                    v = 0.f;
                else
                    v = (float)En[(size_t)(i + 1) * KLENC + delta - 1026];
                bdv[cb][reg] = v;
            }
        }

        // AC tile: S = Q K^T (16 rows x 64 cols per wave)
        f32x4 sa[4];
#pragma unroll
        for (int cb = 0; cb < 4; cb++) sa[cb] = (f32x4){0.f, 0.f, 0.f, 0.f};
#pragma unroll
        for (int kk = 0; kk < 2; kk++) {
            f16x8 aq = *(const f16x8*)&Qs[w * 16 + l15][kk * 32 + quad * 8];
#pragma unroll
            for (int cb = 0; cb < 4; cb++) {
                f16x8 bk = *(const f16x8*)&Ks[cb * 16 + l15][kk * 32 + quad * 8];
                sa[cb] = __builtin_amdgcn_mfma_f32_16x16x32_f16(aq, bk, sa[cb], 0, 0, 0);
            }
        }

        // score + online softmax (rows live in 16-lane quad groups)
        float p[4][4], alpha_[4];
#pragma unroll
        for (int reg = 0; reg < 4; reg++) {
            float sv[4];
#pragma unroll
            for (int cb = 0; cb < 4; cb++) sv[cb] = (sa[cb][reg] + bdv[cb][reg]) * scale;
            float mx = fmaxf(fmaxf(sv[0], sv[1]), fmaxf(sv[2], sv[3]));
#pragma unroll
            for (int off = 1; off < 16; off <<= 1) mx = fmaxf(mx, __shfl_xor(mx, off, 64));
            float mn = fmaxf(m_old[reg], mx);
            float al = __expf(m_old[reg] - mn);
            float ps = 0.f;
#pragma unroll
            for (int cb = 0; cb < 4; cb++) {
                float e = __expf(sv[cb] - mn);
                p[cb][reg] = e; ps += e;
            }
            lsum[reg] = lsum[reg] * al + ps;
            m_old[reg] = mn;
            alpha_[reg] = al;
        }
#pragma unroll
        for (int db = 0; db < 4; db++)
#pragma unroll
            for (int reg = 0; reg < 4; reg++) O[db][reg] *= alpha_[reg];

        // P: C-layout -> LDS -> A-layout (all waves passed s2, prior PV done)
#pragma unroll
        for (int cb = 0; cb < 4; cb++)
#pragma unroll
            for (int reg = 0; reg < 4; reg++)
                Ps[wq + reg][cb * 16 + l15] = (half_t)p[cb][reg];
        __syncthreads();  // s3

        // O += P V
#pragma unroll
        for (int kk = 0; kk < 2; kk++) {
            f16x8 pa = *(const f16x8*)&Ps[w * 16 + l15][kk * 32 + quad * 8];
#pragma unroll
            for (int db = 0; db < 4; db++) {
                f16x8 vb = *(const f16x8*)&Vs[db * 16 + l15][kk * 32 + quad * 8];
                O[db] = __builtin_amdgcn_mfma_f32_16x16x32_f16(pa, vb, O[db], 0, 0, 0);
            }
        }
    }

    // finalize: divide by row sums, write av[i][b][n*64+d] (fp16)
    float inv[4];
#pragma unroll
    for (int reg = 0; reg < 4; reg++) {
        float tot = lsum[reg];
#pragma unroll
        for (int off = 1; off < 16; off <<= 1) tot += __shfl_xor(tot, off, 64);
        inv[reg] = 1.0f / tot;
    }
#pragma unroll
    for (int db = 0; db < 4; db++)
#pragma unroll
        for (int reg = 0; reg < 4; reg++) {
            int i = i0 + wq + reg;
            int col = n * 64 + db * 16 + l15;
            av[((size_t)i * BSZC + b) * DMODELC + col] = (half_t)(O[db][reg] * inv[reg]);
        }
}

// ---------------------------------------------------------------- launch
extern "C" void kernel_launch(void* const* d_in, const int* in_sizes, int n_in,
                              void* d_out, int out_size, void* d_ws, size_t ws_size,
                              hipStream_t stream) {
    const float* w   = (const float*)d_in[0];  // [KLEN, BSZ, DMODEL] fp32
    const float* r   = (const float*)d_in[1];  // [KLEN, DMODEL] fp32
    const float* rwb = (const float*)d_in[2];
    const float* rrb = (const float*)d_in[3];
    const float* Wq  = (const float*)d_in[4];
    const float* Wkv = (const float*)d_in[5];
    const float* Wr  = (const float*)d_in[6];
    const float* Wo  = (const float*)d_in[7];
    float* out = (float*)d_out;

    half_t* ws = (half_t*)d_ws;
    half_t* qw   = ws; ws += (size_t)BSZC * NHC * QLENC * DHC;  // 2M elem
    half_t* qr   = ws; ws += (size_t)BSZC * NHC * QLENC * DHC;  // 2M
    half_t* kh   = ws; ws += (size_t)BSZC * NHC * KLENC * DHC;  // 4M
    half_t* vt   = ws; ws += (size_t)BSZC * NHC * KLENC * DHC;  // 4M
    half_t* rk   = ws; ws += (size_t)NHC * KLENC * DHC;         // 2M
    half_t* av   = ws; ws += (size_t)QLENC * BSZC * DMODELC;    // 2M
    half_t* WqT  = ws; ws += (size_t)DMODELC * DMODELC;         // 1M
    half_t* WkvT = ws; ws += (size_t)2 * DMODELC * DMODELC;     // 2M
    half_t* WrT  = ws; ws += (size_t)DMODELC * DMODELC;         // 1M
    half_t* WoT  = ws; ws += (size_t)DMODELC * DMODELC;         // 1M
    half_t* E    = ws; ws += (size_t)BSZC * NHC * QLENC * KLENC; // 64M elem (128MB)

    dim3 blk(256);
    transpose64<<<dim3(16, 16), blk, 0, stream>>>(Wq, WqT, 1024, 1024);
    transpose64<<<dim3(32, 16), blk, 0, stream>>>(Wkv, WkvT, 1024, 2048);
    transpose64<<<dim3(16, 16), blk, 0, stream>>>(Wr, WrT, 1024, 1024);
    transpose64<<<dim3(16, 16), blk, 0, stream>>>(Wo, WoT, 1024, 1024);

    // q projection: rows = last qlen positions of w -> [2048 x 1024] @ WqT
    gemm64<0><<<dim3(16, 32), blk, 0, stream>>>(
        w + (size_t)QLENC * BSZC * DMODELC, WqT, 1024, 1024, 1024, 0,
        qw, qr, rwb, rrb);
    // kv projection: [4096 x 1024] @ WkvT -> kh + vt
    gemm64<1><<<dim3(32, 64), blk, 0, stream>>>(
        w, WkvT, 1024, 1024, 1024, 0, kh, vt, nullptr, nullptr);
    // r projection: [2048 x 1024] @ WrT -> rk
    gemm64<2><<<dim3(16, 32), blk, 0, stream>>>(
        r, WrT, 1024, 1024, 1024, 0, rk, nullptr, nullptr, nullptr);

    // E-gemm: E[bn] = qr[bn] [1024x64] @ rk[n]^T [2048x64], z = bn
    gemm64<4><<<dim3(32, 16, 32), blk, 0, stream>>>(
        qr, rk, 64, 64, 64, 2048, E, nullptr, nullptr, nullptr);

    // fused attention: grid (heads, q-tiles, batch)
    attn_fused<<<dim3(NHC, QLENC / 64, BSZC), blk, 0, stream>>>(
        qw, kh, vt, E, av);

    // output projection: av [2048 x 1024] fp16 @ WoT -> out fp32
    gemm64<3><<<dim3(16, 32), blk, 0, stream>>>(
        av, WoT, 1024, 1024, 1024, 1024, out, nullptr, nullptr, nullptr);

    (void)in_sizes; (void)n_in; (void)out_size; (void)ws_size;
}

// Round 5
// 341.678 us; speedup vs baseline: 1.4111x; 1.4111x over previous
//
#include <hip/hip_runtime.h>
#include <hip/hip_bf16.h>

// RelMultiHeadAttn (Transformer-XL) on MI355X.
// fp32 inputs/outputs; fp16 internal, fp32 accumulate.
// QLEN=1024 MLEN=1024 KLEN=2048 BSZ=2 DMODEL=1024 NH=16 DH=64
// Round 5: revert to fused windowed-T attention (round-3, 143us known);
// all projections via 128x128-tile GEMM (m93-style); w/r pre-converted fp16.

#define QLENC 1024
#define KLENC 2048
#define BSZC 2
#define DMODELC 1024
#define NHC 16
#define DHC 64

typedef _Float16 half_t;
typedef __attribute__((ext_vector_type(8))) _Float16 f16x8;
typedef __attribute__((ext_vector_type(4))) float f32x4;

// ---------------------------------------------------------------- fp32->fp16
__global__ __launch_bounds__(256) void cvt_f32_f16(const float* __restrict__ s,
                                                   half_t* __restrict__ d) {
    size_t i = ((size_t)blockIdx.x * 256 + threadIdx.x) * 8;
    const float4* sp = (const float4*)(s + i);
    float4 f0 = sp[0], f1 = sp[1];
    half_t h[8];
    h[0] = (half_t)f0.x; h[1] = (half_t)f0.y; h[2] = (half_t)f0.z; h[3] = (half_t)f0.w;
    h[4] = (half_t)f1.x; h[5] = (half_t)f1.y; h[6] = (half_t)f1.z; h[7] = (half_t)f1.w;
    *(uint4*)(d + i) = *(uint4*)&h[0];
}

// ---------------------------------------------------------------- transpose
// W [K x N] fp32 row-major -> Wt [N x K] fp16 row-major. 64x64 tiles.
__global__ __launch_bounds__(256) void transpose64(const float* __restrict__ W,
                                                   half_t* __restrict__ Wt,
                                                   int K, int N) {
    __shared__ __attribute__((aligned(16))) half_t T[64][72];
    int t = threadIdx.x;
    int n0 = blockIdx.x * 64, k0 = blockIdx.y * 64;
    int r = t >> 2, c = (t & 3) << 4;
    const float4* s = (const float4*)&W[(size_t)(k0 + r) * N + n0 + c];
    float4 f0 = s[0], f1 = s[1], f2 = s[2], f3 = s[3];
    half_t h[16];
    h[0] = (half_t)f0.x; h[1] = (half_t)f0.y; h[2] = (half_t)f0.z; h[3] = (half_t)f0.w;
    h[4] = (half_t)f1.x; h[5] = (half_t)f1.y; h[6] = (half_t)f1.z; h[7] = (half_t)f1.w;
    h[8] = (half_t)f2.x; h[9] = (half_t)f2.y; h[10] = (half_t)f2.z; h[11] = (half_t)f2.w;
    h[12] = (half_t)f3.x; h[13] = (half_t)f3.y; h[14] = (half_t)f3.z; h[15] = (half_t)f3.w;
    *(uint4*)&T[r][c] = *(uint4*)&h[0];
    *(uint4*)&T[r][c + 8] = *(uint4*)&h[8];
    __syncthreads();
    half_t vals[16];
#pragma unroll
    for (int u = 0; u < 16; u++) vals[u] = T[c + u][r];
    *(uint4*)&Wt[(size_t)(n0 + r) * K + k0 + c] = *(uint4*)&vals[0];
    *(uint4*)&Wt[(size_t)(n0 + r) * K + k0 + c + 8] = *(uint4*)&vals[8];
}

// ---------------------------------------------------------------- GEMM 128x128
// C = A[M,K] @ Bt[N,K]^T, fp16 in, fp32 acc. 128x128 tile / 256 thr / 4 waves,
// each wave owns a 64x64 subtile (4x4 blocks of 16x16x32 MFMA). BK=64.
// EPI 0: q projection -> qw (+bias1), qr (+bias2), head-split (fp16)
// EPI 1: kv projection -> kh [b][n][j][d], vt [b][n][d][j] (fp16)
// EPI 2: r projection  -> rk [n][t][d] (fp16)
// EPI 3: plain fp32 [M,ldc] output
template <int EPI>
__global__ __launch_bounds__(256) void gemm128(
    const half_t* __restrict__ A, const half_t* __restrict__ Bt,
    int K, int lda, int ldb, int ldc,
    void* __restrict__ o1v, void* __restrict__ o2v,
    const float* __restrict__ bias1, const float* __restrict__ bias2) {
    __shared__ __attribute__((aligned(16))) half_t As[128][72];
    __shared__ __attribute__((aligned(16))) half_t Bs[128][72];

    int t = threadIdx.x;
    int w = t >> 6, ln = t & 63, quad = ln >> 4, l15 = ln & 15;
    int m0 = blockIdx.y * 128, n0 = blockIdx.x * 128;
    int sr = t >> 1, sc = (t & 1) * 32;       // staging: row, col-base (halfs)
    int rbase = 64 * (w >> 1), cbase = 64 * (w & 1);

    f32x4 acc[4][4];
#pragma unroll
    for (int i = 0; i < 4; i++)
#pragma unroll
        for (int j = 0; j < 4; j++) acc[i][j] = (f32x4){0.f, 0.f, 0.f, 0.f};

    for (int k0 = 0; k0 < K; k0 += 64) {
        const uint4* ap = (const uint4*)&A[(size_t)(m0 + sr) * lda + k0 + sc];
        uint4 a0 = ap[0], a1 = ap[1], a2 = ap[2], a3 = ap[3];
        const uint4* bp = (const uint4*)&Bt[(size_t)(n0 + sr) * ldb + k0 + sc];
        uint4 b0 = bp[0], b1 = bp[1], b2 = bp[2], b3 = bp[3];
        __syncthreads();
        *(uint4*)&As[sr][sc] = a0;      *(uint4*)&As[sr][sc + 8] = a1;
        *(uint4*)&As[sr][sc + 16] = a2; *(uint4*)&As[sr][sc + 24] = a3;
        *(uint4*)&Bs[sr][sc] = b0;      *(uint4*)&Bs[sr][sc + 8] = b1;
        *(uint4*)&Bs[sr][sc + 16] = b2; *(uint4*)&Bs[sr][sc + 24] = b3;
        __syncthreads();
#pragma unroll
        for (int kk = 0; kk < 2; kk++) {
            f16x8 af[4], bfr[4];
#pragma unroll
            for (int rb = 0; rb < 4; rb++)
                af[rb] = *(const f16x8*)&As[rbase + rb * 16 + l15][kk * 32 + quad * 8];
#pragma unroll
            for (int cb = 0; cb < 4; cb++)
                bfr[cb] = *(const f16x8*)&Bs[cbase + cb * 16 + l15][kk * 32 + quad * 8];
#pragma unroll
            for (int rb = 0; rb < 4; rb++)
#pragma unroll
                for (int cb = 0; cb < 4; cb++)
                    acc[rb][cb] = __builtin_amdgcn_mfma_f32_16x16x32_f16(
                        af[rb], bfr[cb], acc[rb][cb], 0, 0, 0);
        }
    }

    half_t* o1h = (half_t*)o1v;
    half_t* o2h = (half_t*)o2v;
#pragma unroll
    for (int rb = 0; rb < 4; rb++)
#pragma unroll
        for (int cb = 0; cb < 4; cb++)
#pragma unroll
            for (int reg = 0; reg < 4; reg++) {
                int gr = m0 + rbase + 16 * rb + quad * 4 + reg;  // C row
                int gc = n0 + cbase + 16 * cb + l15;             // C col
                float v = acc[rb][cb][reg];
                if (EPI == 0) {
                    int p_ = gr >> 1, b_ = gr & 1, n_ = gc >> 6, d_ = gc & 63;
                    float bb1 = bias1[gc];
                    float bb2 = bias2[gc];
                    size_t idx = (((size_t)(b_ * NHC + n_)) * QLENC + p_) * DHC + d_;
                    o1h[idx] = (half_t)(v + bb1);
                    o2h[idx] = (half_t)(v + bb2);
                } else if (EPI == 1) {
                    int p_ = gr >> 1, b_ = gr & 1;
                    if (gc < NHC * DHC) {
                        int n_ = gc >> 6, d_ = gc & 63;
                        o1h[(((size_t)(b_ * NHC + n_)) * KLENC + p_) * DHC + d_] = (half_t)v;
                    } else {
                        int c2 = gc - NHC * DHC, n_ = c2 >> 6, d_ = c2 & 63;
                        o2h[(((size_t)(b_ * NHC + n_)) * DHC + d_) * KLENC + p_] = (half_t)v;
                    }
                } else if (EPI == 2) {
                    int n_ = gc >> 6, d_ = gc & 63;
                    o1h[(((size_t)n_) * KLENC + gr) * DHC + d_] = (half_t)v;
                } else {
                    ((float*)o1v)[(size_t)gr * ldc + gc] = v;
                }
            }
}

// ---------------------------------------------------------------- fused attention
// (round-3 structure, known-good at 143us) One block per (head, 64-row q tile,
// batch). Windowed T = Qr @ rk[window]^T in LDS implements rel_shift:
//   delta = j-i: delta<=1024 -> qr_i . rk[1023+delta]   (window mb = 960+D)
//                delta==1025 -> 0
//                delta>=1026 -> qr_{i+1} . rk[delta-1026] (window mb = D-1089)
__global__ __launch_bounds__(256, 2) void attn_fused(
    const half_t* __restrict__ qw, const half_t* __restrict__ qr,
    const half_t* __restrict__ kh, const half_t* __restrict__ vt,
    const half_t* __restrict__ rk, half_t* __restrict__ av) {
    __shared__ __attribute__((aligned(16))) half_t Qs[64][72];
    __shared__ __attribute__((aligned(16))) half_t Qrs[66][72];
    __shared__ __attribute__((aligned(16))) half_t Ks[64][72];
    __shared__ __attribute__((aligned(16))) half_t Vs[64][72];
    __shared__ __attribute__((aligned(16))) half_t RKs[128][72];
    __shared__ __attribute__((aligned(16))) half_t TP[64][136];

    int n = blockIdx.x, i0 = blockIdx.y * 64, b = blockIdx.z;
    int t = threadIdx.x, w = t >> 6, ln = t & 63, quad = ln >> 4, l15 = ln & 15;
    int lr = t >> 2, lc = (t & 3) << 4;
    int wq = w * 16 + quad * 4;
    size_t bn = (size_t)(b * NHC + n);
    const half_t* rkn = rk + (size_t)n * KLENC * DHC;

    {
        const uint4* s1 = (const uint4*)&qw[((bn * QLENC) + i0 + lr) * DHC + lc];
        *(uint4*)&Qs[lr][lc] = s1[0];
        *(uint4*)&Qs[lr][lc + 8] = s1[1];
        const uint4* s2 = (const uint4*)&qr[((bn * QLENC) + i0 + lr) * DHC + lc];
        *(uint4*)&Qrs[lr][lc] = s2[0];
        *(uint4*)&Qrs[lr][lc + 8] = s2[1];
        if (t < 4) {
            int er = i0 + 64; if (er > QLENC - 1) er = QLENC - 1;  // clamped row never read
            const uint4* s3 = (const uint4*)&qr[((bn * QLENC) + er) * DHC + t * 16];
            *(uint4*)&Qrs[64][t * 16] = s3[0];
            *(uint4*)&Qrs[64][t * 16 + 8] = s3[1];
        }
    }

    f32x4 O[4];
#pragma unroll
    for (int i = 0; i < 4; i++) O[i] = (f32x4){0.f, 0.f, 0.f, 0.f};
    float m_old[4] = {-1e30f, -1e30f, -1e30f, -1e30f};
    float lsum[4] = {0.f, 0.f, 0.f, 0.f};
    const float scale = 0.125f;  // 1/sqrt(64)

    for (int jt = 0; jt < KLENC / 64; jt++) {
        int j0 = jt * 64;
        int D = j0 - i0;
        bool need1 = (D <= 1024), need2 = (D >= 1024);  // block-uniform

        const uint4* ks = (const uint4*)&kh[((bn * KLENC) + j0 + lr) * DHC + lc];
        const uint4* vs = (const uint4*)&vt[((bn * DHC) + lr) * KLENC + j0 + lc];
        uint4 k0v = ks[0], k1v = ks[1], v0v = vs[0], v1v = vs[1];
        int mb = need1 ? (960 + D) : (D - 1089);
        int rrl = t >> 1, rh = (t & 1) * 32;
        int rrow = mb + rrl; rrow = rrow < 0 ? 0 : (rrow > KLENC - 1 ? KLENC - 1 : rrow);
        const uint4* rs = (const uint4*)&rkn[(size_t)rrow * DHC + rh];
        uint4 r0 = rs[0], r1 = rs[1], r2 = rs[2], r3 = rs[3];

        __syncthreads();  // s1
        *(uint4*)&Ks[lr][lc] = k0v; *(uint4*)&Ks[lr][lc + 8] = k1v;
        *(uint4*)&Vs[lr][lc] = v0v; *(uint4*)&Vs[lr][lc + 8] = v1v;
        *(uint4*)&RKs[rrl][rh] = r0;      *(uint4*)&RKs[rrl][rh + 8] = r1;
        *(uint4*)&RKs[rrl][rh + 16] = r2; *(uint4*)&RKs[rrl][rh + 24] = r3;
        __syncthreads();  // s2

        f32x4 sa[4];
#pragma unroll
        for (int cb = 0; cb < 4; cb++) sa[cb] = (f32x4){0.f, 0.f, 0.f, 0.f};
#pragma unroll
        for (int kk = 0; kk < 2; kk++) {
            f16x8 aq = *(const f16x8*)&Qs[w * 16 + l15][kk * 32 + quad * 8];
#pragma unroll
            for (int cb = 0; cb < 4; cb++) {
                f16x8 bk = *(const f16x8*)&Ks[cb * 16 + l15][kk * 32 + quad * 8];
                sa[cb] = __builtin_amdgcn_mfma_f32_16x16x32_f16(aq, bk, sa[cb], 0, 0, 0);
            }
        }

        float bdv[4][4];
#pragma unroll
        for (int cb = 0; cb < 4; cb++)
#pragma unroll
            for (int reg = 0; reg < 4; reg++) bdv[cb][reg] = 0.f;

        if (need1) {
            f32x4 tacc[8];
#pragma unroll
            for (int c8 = 0; c8 < 8; c8++) tacc[c8] = (f32x4){0.f, 0.f, 0.f, 0.f};
#pragma unroll
            for (int kk = 0; kk < 2; kk++) {
                f16x8 aq = *(const f16x8*)&Qrs[w * 16 + l15][kk * 32 + quad * 8];
#pragma unroll
                for (int c8 = 0; c8 < 8; c8++) {
                    f16x8 bk = *(const f16x8*)&RKs[c8 * 16 + l15][kk * 32 + quad * 8];
                    tacc[c8] = __builtin_amdgcn_mfma_f32_16x16x32_f16(aq, bk, tacc[c8], 0, 0, 0);
                }
            }
#pragma unroll
            for (int c8 = 0; c8 < 8; c8++)
#pragma unroll
                for (int reg = 0; reg < 4; reg++)
                    TP[wq + reg][c8 * 16 + l15] = (half_t)tacc[c8][reg];
            __syncthreads();  // s3
#pragma unroll
            for (int reg = 0; reg < 4; reg++) {
                int ic = wq + reg;
#pragma unroll
                for (int cb = 0; cb < 4; cb++) {
                    int jc = cb * 16 + l15;
                    int delta = D + jc - ic;
                    if (delta <= 1024) bdv[cb][reg] = (float)TP[ic][63 + jc - ic];
                }
            }
        }
        if (need2) {
            if (need1) {  // mixed tile (D==1024): restage window 2
                int mb2 = D - 1089;
                int rrow2 = mb2 + rrl; rrow2 = rrow2 < 0 ? 0 : (rrow2 > KLENC - 1 ? KLENC - 1 : rrow2);
                const uint4* rs2 = (const uint4*)&rkn[(size_t)rrow2 * DHC + rh];
                uint4 q0 = rs2[0], q1 = rs2[1], q2 = rs2[2], q3 = rs2[3];
                __syncthreads();  // s4
                *(uint4*)&RKs[rrl][rh] = q0;      *(uint4*)&RKs[rrl][rh + 8] = q1;
                *(uint4*)&RKs[rrl][rh + 16] = q2; *(uint4*)&RKs[rrl][rh + 24] = q3;
                __syncthreads();  // s5
            }
            f32x4 tacc[8];
#pragma unroll
            for (int c8 = 0; c8 < 8; c8++) tacc[c8] = (f32x4){0.f, 0.f, 0.f, 0.f};
#pragma unroll
            for (int kk = 0; kk < 2; kk++) {
                f16x8 aq = *(const f16x8*)&Qrs[w * 16 + l15 + 1][kk * 32 + quad * 8];
#pragma unroll
                for (int c8 = 0; c8 < 8; c8++) {
                    f16x8 bk = *(const f16x8*)&RKs[c8 * 16 + l15][kk * 32 + quad * 8];
                    tacc[c8] = __builtin_amdgcn_mfma_f32_16x16x32_f16(aq, bk, tacc[c8], 0, 0, 0);
                }
            }
#pragma unroll
            for (int c8 = 0; c8 < 8; c8++)
#pragma unroll
                for (int reg = 0; reg < 4; reg++)
                    TP[wq + reg][c8 * 16 + l15] = (half_t)tacc[c8][reg];
            __syncthreads();  // s6
#pragma unroll
            for (int reg = 0; reg < 4; reg++) {
                int ic = wq + reg;
#pragma unroll
                for (int cb = 0; cb < 4; cb++) {
                    int jc = cb * 16 + l15;
                    int delta = D + jc - ic;
                    if (delta >= 1026) bdv[cb][reg] = (float)TP[ic][63 + jc - ic];
                }
            }
        }

        float p[4][4], alpha_[4];
#pragma unroll
        for (int reg = 0; reg < 4; reg++) {
            float sv[4];
#pragma unroll
            for (int cb = 0; cb < 4; cb++) sv[cb] = (sa[cb][reg] + bdv[cb][reg]) * scale;
            float mx = fmaxf(fmaxf(sv[0], sv[1]), fmaxf(sv[2], sv[3]));
#pragma unroll
            for (int off = 1; off < 16; off <<= 1) mx = fmaxf(mx, __shfl_xor(mx, off, 64));
            float mn = fmaxf(m_old[reg], mx);
            float al = __expf(m_old[reg] - mn);
            float ps = 0.f;
#pragma unroll
            for (int cb = 0; cb < 4; cb++) {
                float e = __expf(sv[cb] - mn);
                p[cb][reg] = e; ps += e;
            }
            lsum[reg] = lsum[reg] * al + ps;
            m_old[reg] = mn;
            alpha_[reg] = al;
        }
#pragma unroll
        for (int db = 0; db < 4; db++)
#pragma unroll
            for (int reg = 0; reg < 4; reg++) O[db][reg] *= alpha_[reg];

        __syncthreads();  // s7
#pragma unroll
        for (int cb = 0; cb < 4; cb++)
#pragma unroll
            for (int reg = 0; reg < 4; reg++)
                TP[wq + reg][cb * 16 + l15] = (half_t)p[cb][reg];
        __syncthreads();  // s8

#pragma unroll
        for (int kk = 0; kk < 2; kk++) {
            f16x8 pa = *(const f16x8*)&TP[w * 16 + l15][kk * 32 + quad * 8];
#pragma unroll
            for (int db = 0; db < 4; db++) {
                f16x8 vb = *(const f16x8*)&Vs[db * 16 + l15][kk * 32 + quad * 8];
                O[db] = __builtin_amdgcn_mfma_f32_16x16x32_f16(pa, vb, O[db], 0, 0, 0);
            }
        }
    }

    float inv[4];
#pragma unroll
    for (int reg = 0; reg < 4; reg++) {
        float tot = lsum[reg];
#pragma unroll
        for (int off = 1; off < 16; off <<= 1) tot += __shfl_xor(tot, off, 64);
        inv[reg] = 1.0f / tot;
    }
#pragma unroll
    for (int db = 0; db < 4; db++)
#pragma unroll
        for (int reg = 0; reg < 4; reg++) {
            int i = i0 + wq + reg;
            int col = n * 64 + db * 16 + l15;
            av[((size_t)i * BSZC + b) * DMODELC + col] = (half_t)(O[db][reg] * inv[reg]);
        }
}

// ---------------------------------------------------------------- launch
extern "C" void kernel_launch(void* const* d_in, const int* in_sizes, int n_in,
                              void* d_out, int out_size, void* d_ws, size_t ws_size,
                              hipStream_t stream) {
    const float* w   = (const float*)d_in[0];  // [KLEN, BSZ, DMODEL] fp32
    const float* r   = (const float*)d_in[1];  // [KLEN, DMODEL] fp32
    const float* rwb = (const float*)d_in[2];
    const float* rrb = (const float*)d_in[3];
    const float* Wq  = (const float*)d_in[4];
    const float* Wkv = (const float*)d_in[5];
    const float* Wr  = (const float*)d_in[6];
    const float* Wo  = (const float*)d_in[7];
    float* out = (float*)d_out;

    half_t* ws = (half_t*)d_ws;
    half_t* qw   = ws; ws += (size_t)BSZC * NHC * QLENC * DHC;  // 2M elem
    half_t* qr   = ws; ws += (size_t)BSZC * NHC * QLENC * DHC;  // 2M
    half_t* kh   = ws; ws += (size_t)BSZC * NHC * KLENC * DHC;  // 4M
    half_t* vt   = ws; ws += (size_t)BSZC * NHC * KLENC * DHC;  // 4M
    half_t* rk   = ws; ws += (size_t)NHC * KLENC * DHC;         // 2M
    half_t* av   = ws; ws += (size_t)QLENC * BSZC * DMODELC;    // 2M
    half_t* WqT  = ws; ws += (size_t)DMODELC * DMODELC;         // 1M
    half_t* WkvT = ws; ws += (size_t)2 * DMODELC * DMODELC;     // 2M
    half_t* WrT  = ws; ws += (size_t)DMODELC * DMODELC;         // 1M
    half_t* WoT  = ws; ws += (size_t)DMODELC * DMODELC;         // 1M
    half_t* wh   = ws; ws += (size_t)KLENC * BSZC * DMODELC;    // 4M
    half_t* rh   = ws; ws += (size_t)KLENC * DMODELC;           // 2M => ~54 MB

    dim3 blk(256);
    // input conversions fp32 -> fp16
    cvt_f32_f16<<<dim3((KLENC * BSZC * DMODELC) / 2048), blk, 0, stream>>>(w, wh);
    cvt_f32_f16<<<dim3((KLENC * DMODELC) / 2048), blk, 0, stream>>>(r, rh);

    transpose64<<<dim3(16, 16), blk, 0, stream>>>(Wq, WqT, 1024, 1024);
    transpose64<<<dim3(32, 16), blk, 0, stream>>>(Wkv, WkvT, 1024, 2048);
    transpose64<<<dim3(16, 16), blk, 0, stream>>>(Wr, WrT, 1024, 1024);
    transpose64<<<dim3(16, 16), blk, 0, stream>>>(Wo, WoT, 1024, 1024);

    // q projection: last qlen positions of wh -> [2048 x 1024] @ WqT
    gemm128<0><<<dim3(8, 16), blk, 0, stream>>>(
        wh + (size_t)QLENC * BSZC * DMODELC, WqT, 1024, 1024, 1024, 0,
        qw, qr, rwb, rrb);
    // kv projection: [4096 x 1024] @ WkvT -> kh + vt
    gemm128<1><<<dim3(16, 32), blk, 0, stream>>>(
        wh, WkvT, 1024, 1024, 1024, 0, kh, vt, nullptr, nullptr);
    // r projection: [2048 x 1024] @ WrT -> rk
    gemm128<2><<<dim3(8, 16), blk, 0, stream>>>(
        rh, WrT, 1024, 1024, 1024, 0, rk, nullptr, nullptr, nullptr);

    // fused attention: grid (heads, q-tiles, batch)
    attn_fused<<<dim3(NHC, QLENC / 64, BSZC), blk, 0, stream>>>(
        qw, qr, kh, vt, rk, av);

    // output projection: av [2048 x 1024] fp16 @ WoT -> out fp32
    gemm128<3><<<dim3(8, 16), blk, 0, stream>>>(
        av, WoT, 1024, 1024, 1024, 1024, out, nullptr, nullptr, nullptr);

    (void)in_sizes; (void)n_in; (void)out_size; (void)ws_size;
}